// Round 1
// baseline (2235.364 us; speedup 1.0000x reference)
//
#include <hip/hip_runtime.h>
#include <math.h>

#define NB 2
#define NPTS 4096
#define CH 64
#define PATCH 64
#define K2 16
#define NRAD 4

// ---------------------------------------------------------------------------
// Kernel 1: exact 64-NN per point via radix select on float bits.
// One block (256 threads) per query point. Distances staged in LDS.
// ---------------------------------------------------------------------------
__global__ __launch_bounds__(256) void knn_kernel(const float* __restrict__ xyz,
                                                  int* __restrict__ knn_idx,
                                                  float* __restrict__ knn_sqd) {
    const int pt = blockIdx.x;          // 0 .. NB*NPTS-1
    const int b  = pt >> 12;
    const int q  = pt & (NPTS - 1);
    const int tid = threadIdx.x;

    __shared__ float sd[NPTS];          // 16 KB
    __shared__ unsigned hist[256];
    __shared__ unsigned cum[256];
    __shared__ unsigned sh_prefix;
    __shared__ int sh_need;
    __shared__ int cnt_less, cnt_tie;

    const float qx = xyz[(b * NPTS + q) * 3 + 0];
    const float qy = xyz[(b * NPTS + q) * 3 + 1];
    const float qz = xyz[(b * NPTS + q) * 3 + 2];

    for (int m = tid; m < NPTS; m += 256) {
        float dx = xyz[(b * NPTS + m) * 3 + 0] - qx;
        float dy = xyz[(b * NPTS + m) * 3 + 1] - qy;
        float dz = xyz[(b * NPTS + m) * 3 + 2] - qz;
        sd[m] = dx * dx + dy * dy + dz * dz;
    }
    if (tid == 0) { sh_prefix = 0u; sh_need = PATCH; cnt_less = 0; cnt_tie = 0; }
    __syncthreads();

    // 4 radix passes (8-bit digits, MSB first) to find the exact 64th-smallest key.
    for (int shift = 24; shift >= 0; shift -= 8) {
        hist[tid] = 0u;
        __syncthreads();
        const unsigned prefix = sh_prefix;
        const unsigned mask_hi = (shift == 24) ? 0u : (0xFFFFFFFFu << (shift + 8));
        for (int m = tid; m < NPTS; m += 256) {
            unsigned key = __float_as_uint(sd[m]);
            if ((key & mask_hi) == prefix)
                atomicAdd(&hist[(key >> shift) & 0xFFu], 1u);
        }
        __syncthreads();
        // inclusive scan over 256 bins (Hillis-Steele)
        unsigned cnt = hist[tid];
        cum[tid] = cnt;
        __syncthreads();
        for (int off = 1; off < 256; off <<= 1) {
            unsigned v = (tid >= off) ? cum[tid - off] : 0u;
            __syncthreads();
            cum[tid] += v;
            __syncthreads();
        }
        const int need = sh_need;
        const unsigned pfx = sh_prefix;
        const unsigned incl = cum[tid];
        const unsigned excl = incl - cnt;
        __syncthreads();  // all reads of sh_need/sh_prefix done before the write
        if ((int)excl < need && need <= (int)incl) {   // unique crossing thread
            sh_prefix = pfx | ((unsigned)tid << shift);
            sh_need   = need - (int)excl;
        }
        __syncthreads();
    }

    const unsigned T = sh_prefix;       // key of the 64th-smallest distance
    const int need   = sh_need;         // how many ties at T to keep
    const int nless  = PATCH - need;

    for (int m = tid; m < NPTS; m += 256) {
        unsigned key = __float_as_uint(sd[m]);
        if (key < T) {
            int pos = atomicAdd(&cnt_less, 1);
            knn_idx[pt * PATCH + pos] = m;
            knn_sqd[pt * PATCH + pos] = sd[m];
        } else if (key == T) {
            int pos = atomicAdd(&cnt_tie, 1);
            if (pos < need) {
                knn_idx[pt * PATCH + nless + pos] = m;
                knn_sqd[pt * PATCH + nless + pos] = sd[m];
            }
        }
    }
}

// ---------------------------------------------------------------------------
// Kernel 2: per-point conv. One block (256 threads) per point.
//   phase 1: Y[16], rad[4] per neighbor; y_w wave-reduce
//   phase 2: ck[p][rk] = Y[p][k]*rad[p][r]/denom in LDS; gather signal to LDS
//   phase 3: y[c][rk] = sum_p ck[p][rk]*sig[p][c]  (4x4 register tiles)
//   phase 4: square, band-sum (LDS atomics), sqrt-clamp
//   phase 5: out[i] = sum_j W[i][j]*z[j] + bias
// ---------------------------------------------------------------------------
__global__ __launch_bounds__(256) void conv_kernel(const float* __restrict__ xyz,
                                                   const float* __restrict__ signal,
                                                   const float* __restrict__ weight,
                                                   const float* __restrict__ biases,
                                                   const int* __restrict__ knn_idx,
                                                   const float* __restrict__ knn_sqd,
                                                   float* __restrict__ out) {
    const int pt = blockIdx.x;
    const int b  = pt >> 12;
    const int q  = pt & (NPTS - 1);
    const int tid = threadIdx.x;

    __shared__ float Ys[PATCH][K2];       // 4 KB
    __shared__ float rads[PATCH][NRAD];   // 1 KB
    __shared__ int   sIdx[PATCH];
    __shared__ float ck[PATCH][64];       // 16 KB   rk = r*16 + k
    __shared__ float sigs[PATCH][64];     // 16 KB
    __shared__ float z2[1024];            // 4 KB    j = c*16 + r*4 + l
    __shared__ float partial[4][64];      // 1 KB
    __shared__ float sh_yw;

    // ---- phase 1 (wave 0 only: lanes 0..63 = one full wavefront) ----
    if (tid < PATCH) {
        const int p = tid;
        const int idx = knn_idx[pt * PATCH + p];
        sIdx[p] = idx;
        const float sqd = knn_sqd[pt * PATCH + p];
        const float cx = xyz[(b * NPTS + q) * 3 + 0];
        const float cy = xyz[(b * NPTS + q) * 3 + 1];
        const float cz = xyz[(b * NPTS + q) * 3 + 2];
        const float dx = xyz[(b * NPTS + idx) * 3 + 0] - cx;
        const float dy = xyz[(b * NPTS + idx) * 3 + 1] - cy;
        const float dz = xyz[(b * NPTS + idx) * 3 + 2] - cz;
        const float nrm = sqrtf(dx * dx + dy * dy + dz * dz);
        const float inv_n = 1.0f / fmaxf(nrm, 0.01f);
        const float x = dx * inv_n, y = dy * inv_n, z = dz * inv_n;
        const float x2 = x * x, y2 = y * y, zz = z * z;

        Ys[p][0] = 0.28209479177387814f;                       // Y00
        const float s3 = 0.4886025119029199f;                  // sqrt(3/pi)/2
        Ys[p][1] = s3 * y;  Ys[p][2] = s3 * z;  Ys[p][3] = -s3 * x;
        const float s15h = 1.0925484305920792f;                // sqrt(15/pi)/2
        const float s15q = 0.5462742152960396f;                // sqrt(15/pi)/4
        const float s5q  = 0.31539156525252005f;               // sqrt(5/pi)/4
        Ys[p][4] = s15h * x * y;
        Ys[p][5] = s15h * y * z;
        Ys[p][6] = s5q * (2.0f * zz - x2 - y2);
        Ys[p][7] = -s15h * z * x;
        Ys[p][8] = s15q * (x2 - y2);
        const float c33  = 0.5900435899266435f;                // sqrt(35/(2pi))/4
        const float c32  = 2.8906114426405543f;                // sqrt(105/pi)/2
        const float c31  = 0.4570457994644658f;                // sqrt(21/(2pi))/4
        const float c30  = 0.3731763325901154f;                // sqrt(7/pi)/4
        const float c32b = 1.4453057213202771f;                // sqrt(105/pi)/4
        Ys[p][9]  = c33 * (3.0f * x2 * y - y * y2);
        Ys[p][10] = c32 * x * y * z;
        Ys[p][11] = c31 * (4.0f * y * zz - x2 * y - y * y2);
        Ys[p][12] = c30 * (2.0f * z * zz - 3.0f * x2 * z - 3.0f * y2 * z);
        Ys[p][13] = -c31 * (4.0f * zz * x - x * x2 - x * y2);
        Ys[p][14] = c32b * (x2 * z - y2 * z);
        Ys[p][15] = -c33 * (x * x2 - 3.0f * x * y2);

        const float dist = sqrtf(fmaxf(sqd, 1e-4f));
        // sigma = 0.5/3 -> 1/(2 sigma^2) = 18
        const float d0 = dist;
        const float d1 = dist - 0.16666667f;
        const float d2 = dist - 0.33333334f;
        const float d3 = dist - 0.5f;
        const float r0 = expf(-d0 * d0 * 18.0f);
        rads[p][0] = r0;
        rads[p][1] = expf(-d1 * d1 * 18.0f);
        rads[p][2] = expf(-d2 * d2 * 18.0f);
        rads[p][3] = expf(-d3 * d3 * 18.0f);

        float v = 0.28209479177387814f * r0;   // y_w contribution
        for (int off = 32; off > 0; off >>= 1) v += __shfl_down(v, off);
        if (p == 0) sh_yw = v;
    }
    for (int i = tid; i < 1024; i += 256) z2[i] = 0.0f;
    __syncthreads();

    // ---- phase 2 ----
    const float inv_den = 1.0f / (sh_yw + 1e-6f);
#pragma unroll
    for (int i = 0; i < 16; ++i) {
        int v = i * 256 + tid;
        int p = v >> 6, rk = v & 63, r = rk >> 4, k = rk & 15;
        ck[p][rk] = Ys[p][k] * rads[p][r] * inv_den;
    }
#pragma unroll
    for (int i = 0; i < 16; ++i) {
        int v = i * 256 + tid;
        int p = v >> 6, c = v & 63;
        sigs[p][c] = signal[(size_t)(b * NPTS + sIdx[p]) * CH + c];
    }
    __syncthreads();

    // ---- phase 3: 4x4 register-tile matmul over p ----
    const int c0  = (tid & 15) * 4;
    const int rk0 = (tid >> 4) * 4;
    float acc[4][4] = {};
#pragma unroll
    for (int p = 0; p < PATCH; ++p) {
        const float4 s  = *(const float4*)&sigs[p][c0];
        const float4 kk = *(const float4*)&ck[p][rk0];
        acc[0][0] += s.x * kk.x; acc[0][1] += s.x * kk.y; acc[0][2] += s.x * kk.z; acc[0][3] += s.x * kk.w;
        acc[1][0] += s.y * kk.x; acc[1][1] += s.y * kk.y; acc[1][2] += s.y * kk.z; acc[1][3] += s.y * kk.w;
        acc[2][0] += s.z * kk.x; acc[2][1] += s.z * kk.y; acc[2][2] += s.z * kk.z; acc[2][3] += s.z * kk.w;
        acc[3][0] += s.w * kk.x; acc[3][1] += s.w * kk.y; acc[3][2] += s.w * kk.z; acc[3][3] += s.w * kk.w;
    }

    // ---- phase 4: square + band accumulation ----
    // bands over k: l=0:{0} l=1:{1..3} l=2:{4..8} l=3:{9..15}
    const int r  = rk0 >> 4;
    const int k0 = rk0 & 15;
#pragma unroll
    for (int ci = 0; ci < 4; ++ci) {
        const int c = c0 + ci;
        const float a0 = acc[ci][0] * acc[ci][0];
        const float a1 = acc[ci][1] * acc[ci][1];
        const float a2 = acc[ci][2] * acc[ci][2];
        const float a3 = acc[ci][3] * acc[ci][3];
        const int base = c * 16 + r * 4;
        if (k0 == 0) {
            atomicAdd(&z2[base + 0], a0);
            atomicAdd(&z2[base + 1], a1 + a2 + a3);
        } else if (k0 == 4) {
            atomicAdd(&z2[base + 2], a0 + a1 + a2 + a3);
        } else if (k0 == 8) {
            atomicAdd(&z2[base + 2], a0);
            atomicAdd(&z2[base + 3], a1 + a2 + a3);
        } else {
            atomicAdd(&z2[base + 3], a0 + a1 + a2 + a3);
        }
    }
    __syncthreads();
    for (int i = tid; i < 1024; i += 256) z2[i] = sqrtf(fmaxf(z2[i], 1e-4f));
    __syncthreads();

    // ---- phase 5: out[i] = sum_j W[i][j] * z[j] ----
    const int i_out = tid & 63;
    const int part  = tid >> 6;
    const float4* wrow = (const float4*)(weight + (size_t)i_out * 1024 + part * 256);
    const float4* zp   = (const float4*)(&z2[part * 256]);
    float s = 0.0f;
#pragma unroll
    for (int j = 0; j < 64; ++j) {
        const float4 w4 = wrow[j];
        const float4 z4 = zp[j];
        s += w4.x * z4.x + w4.y * z4.y + w4.z * z4.z + w4.w * z4.w;
    }
    partial[part][i_out] = s;
    __syncthreads();
    if (tid < 64) {
        out[(size_t)pt * CH + tid] =
            partial[0][tid] + partial[1][tid] + partial[2][tid] + partial[3][tid] + biases[tid];
    }
}

extern "C" void kernel_launch(void* const* d_in, const int* in_sizes, int n_in,
                              void* d_out, int out_size, void* d_ws, size_t ws_size,
                              hipStream_t stream) {
    const float* xyz    = (const float*)d_in[0];
    const float* signal = (const float*)d_in[1];
    const float* weight = (const float*)d_in[2];
    const float* biases = (const float*)d_in[3];
    float* out = (float*)d_out;

    int*   knn_idx = (int*)d_ws;
    float* knn_sqd = (float*)((char*)d_ws + (size_t)NB * NPTS * PATCH * sizeof(int));

    knn_kernel<<<NB * NPTS, 256, 0, stream>>>(xyz, knn_idx, knn_sqd);
    conv_kernel<<<NB * NPTS, 256, 0, stream>>>(xyz, signal, weight, biases,
                                               knn_idx, knn_sqd, out);
}

// Round 2
// 250.043 us; speedup vs baseline: 8.9399x; 8.9399x over previous
//
#include <hip/hip_runtime.h>
#include <math.h>

#define NB 2
#define NPTS 4096
#define CH 64
#define PATCH 64
#define K2 16
#define NRAD 4

// ---------------------------------------------------------------------------
// Kernel 0: transpose weight (64 x 1024, row-major) -> WT (1024 x 64) so the
// conv epilogue reads it lane-coalesced.
// ---------------------------------------------------------------------------
__global__ __launch_bounds__(256) void wtrans_kernel(const float* __restrict__ W,
                                                     float* __restrict__ WT) {
    const int idx = blockIdx.x * 256 + threadIdx.x;   // 65536 total
    const int i = idx >> 10;          // out channel
    const int j = idx & 1023;         // composite (in, r, l)
    WT[j * 64 + i] = W[idx];
}

// ---------------------------------------------------------------------------
// Kernel 1: exact 64-NN per point via radix select on float bits.
// One block (256 threads) per query point. Distances staged in LDS.
// Digit selection per pass is done by wave 0 with a shfl scan (no barriers
// inside the scan).
// ---------------------------------------------------------------------------
__global__ __launch_bounds__(256) void knn_kernel(const float* __restrict__ xyz,
                                                  int* __restrict__ knn_idx,
                                                  float* __restrict__ knn_sqd) {
    const int pt = blockIdx.x;          // 0 .. NB*NPTS-1
    const int b  = pt >> 12;
    const int q  = pt & (NPTS - 1);
    const int tid = threadIdx.x;

    __shared__ float sd[NPTS];          // 16 KB
    __shared__ unsigned hist[256];
    __shared__ unsigned sh_prefix;
    __shared__ int sh_need;
    __shared__ int cnt_less, cnt_tie;

    const float qx = xyz[(b * NPTS + q) * 3 + 0];
    const float qy = xyz[(b * NPTS + q) * 3 + 1];
    const float qz = xyz[(b * NPTS + q) * 3 + 2];

    for (int m = tid; m < NPTS; m += 256) {
        float dx = xyz[(b * NPTS + m) * 3 + 0] - qx;
        float dy = xyz[(b * NPTS + m) * 3 + 1] - qy;
        float dz = xyz[(b * NPTS + m) * 3 + 2] - qz;
        sd[m] = dx * dx + dy * dy + dz * dz;
    }
    if (tid == 0) { sh_prefix = 0u; sh_need = PATCH; cnt_less = 0; cnt_tie = 0; }
    __syncthreads();

    // 4 radix passes (8-bit digits, MSB first) -> exact 64th-smallest key.
    for (int shift = 24; shift >= 0; shift -= 8) {
        hist[tid] = 0u;
        __syncthreads();
        const unsigned prefix = sh_prefix;
        const unsigned mask_hi = (shift == 24) ? 0u : (0xFFFFFFFFu << (shift + 8));
        for (int m = tid; m < NPTS; m += 256) {
            unsigned key = __float_as_uint(sd[m]);
            if ((key & mask_hi) == prefix)
                atomicAdd(&hist[(key >> shift) & 0xFFu], 1u);
        }
        __syncthreads();
        if (tid < 64) {                       // wave 0: scan 256 bins, pick digit
            const int L = tid;
            const unsigned s0 = hist[4 * L + 0];
            const unsigned s1 = hist[4 * L + 1];
            const unsigned s2 = hist[4 * L + 2];
            const unsigned s3 = hist[4 * L + 3];
            const unsigned tot = s0 + s1 + s2 + s3;
            unsigned run = tot;               // inclusive scan over 64 lanes
#pragma unroll
            for (int off = 1; off < 64; off <<= 1) {
                unsigned v = __shfl_up(run, off);
                if (L >= off) run += v;
            }
            const unsigned excl = run - tot;
            const int need = sh_need;         // wave-lockstep: reads before write below
            const unsigned pfx = sh_prefix;
            const unsigned c0 = excl + s0, c1 = c0 + s1, c2 = c1 + s2, c3 = c2 + s3;
            int bin = -1; unsigned eb = 0u;
            if ((int)excl < need && need <= (int)c0)      { bin = 4 * L + 0; eb = excl; }
            else if ((int)c0 < need && need <= (int)c1)   { bin = 4 * L + 1; eb = c0; }
            else if ((int)c1 < need && need <= (int)c2)   { bin = 4 * L + 2; eb = c1; }
            else if ((int)c2 < need && need <= (int)c3)   { bin = 4 * L + 3; eb = c2; }
            if (bin >= 0) {
                sh_prefix = pfx | ((unsigned)bin << shift);
                sh_need   = need - (int)eb;
            }
        }
        __syncthreads();
    }

    const unsigned T = sh_prefix;       // key of the 64th-smallest distance
    const int need   = sh_need;         // how many ties at T to keep
    const int nless  = PATCH - need;

    for (int m = tid; m < NPTS; m += 256) {
        unsigned key = __float_as_uint(sd[m]);
        if (key < T) {
            int pos = atomicAdd(&cnt_less, 1);
            knn_idx[pt * PATCH + pos] = m;
            knn_sqd[pt * PATCH + pos] = sd[m];
        } else if (key == T) {
            int pos = atomicAdd(&cnt_tie, 1);
            if (pos < need) {
                knn_idx[pt * PATCH + nless + pos] = m;
                knn_sqd[pt * PATCH + nless + pos] = sd[m];
            }
        }
    }
}

// ---------------------------------------------------------------------------
// Kernel 2: per-point conv. One block (256 threads) per point.
//   phase 1 (wave 0): Y[16], rad[4] per neighbor; ck[p][rk]=Y*rad (swizzled);
//                     y_w shfl-reduce
//   phase 2: gather signal*inv_den into LDS (float4)
//   phase 3: thread owns (c, r): acc[16] over p  (no atomics)
//   phase 4: square, band-sum in registers, sqrt-clamp, float4 store to z2
//   phase 5: out[i] = sum_j WT[j*64+i]*z2[j] + bias (coalesced)
// ---------------------------------------------------------------------------
__global__ __launch_bounds__(256, 4) void conv_kernel(const float* __restrict__ xyz,
                                                      const float* __restrict__ signal,
                                                      const float* __restrict__ WT,
                                                      const float* __restrict__ biases,
                                                      const int* __restrict__ knn_idx,
                                                      const float* __restrict__ knn_sqd,
                                                      float* __restrict__ out) {
    const int pt = blockIdx.x;
    const int b  = pt >> 12;
    const int q  = pt & (NPTS - 1);
    const int tid = threadIdx.x;

    __shared__ float ck[PATCH][64];       // 16 KB; float4 col swizzled by ^(p&15)
    __shared__ float sigs[PATCH][64];     // 16 KB; pre-scaled by inv_den
    __shared__ float z2[1024];            // 4 KB    j = c*16 + r*4 + l
    __shared__ int   sIdx[PATCH];
    __shared__ float partial[4][64];      // 1 KB
    __shared__ float sh_yw;

    // ---- phase 1 (wave 0 only) ----
    if (tid < PATCH) {
        const int p = tid;
        const int idx = knn_idx[pt * PATCH + p];
        sIdx[p] = idx;
        const float sqd = knn_sqd[pt * PATCH + p];
        const float cx = xyz[(b * NPTS + q) * 3 + 0];
        const float cy = xyz[(b * NPTS + q) * 3 + 1];
        const float cz = xyz[(b * NPTS + q) * 3 + 2];
        const float dx = xyz[(b * NPTS + idx) * 3 + 0] - cx;
        const float dy = xyz[(b * NPTS + idx) * 3 + 1] - cy;
        const float dz = xyz[(b * NPTS + idx) * 3 + 2] - cz;
        const float nrm = sqrtf(dx * dx + dy * dy + dz * dz);
        const float inv_n = 1.0f / fmaxf(nrm, 0.01f);
        const float x = dx * inv_n, y = dy * inv_n, z = dz * inv_n;
        const float x2 = x * x, y2 = y * y, zz = z * z;

        float Y[16];
        Y[0] = 0.28209479177387814f;
        const float s3 = 0.4886025119029199f;
        Y[1] = s3 * y;  Y[2] = s3 * z;  Y[3] = -s3 * x;
        const float s15h = 1.0925484305920792f;
        const float s15q = 0.5462742152960396f;
        const float s5q  = 0.31539156525252005f;
        Y[4] = s15h * x * y;
        Y[5] = s15h * y * z;
        Y[6] = s5q * (2.0f * zz - x2 - y2);
        Y[7] = -s15h * z * x;
        Y[8] = s15q * (x2 - y2);
        const float c33  = 0.5900435899266435f;
        const float c32  = 2.8906114426405543f;
        const float c31  = 0.4570457994644658f;
        const float c30  = 0.3731763325901154f;
        const float c32b = 1.4453057213202771f;
        Y[9]  = c33 * (3.0f * x2 * y - y * y2);
        Y[10] = c32 * x * y * z;
        Y[11] = c31 * (4.0f * y * zz - x2 * y - y * y2);
        Y[12] = c30 * (2.0f * z * zz - 3.0f * x2 * z - 3.0f * y2 * z);
        Y[13] = -c31 * (4.0f * zz * x - x * x2 - x * y2);
        Y[14] = c32b * (x2 * z - y2 * z);
        Y[15] = -c33 * (x * x2 - 3.0f * x * y2);

        const float dist = sqrtf(fmaxf(sqd, 1e-4f));
        const float d0 = dist;
        const float d1 = dist - 0.16666667f;
        const float d2 = dist - 0.33333334f;
        const float d3 = dist - 0.5f;
        float rad[4];
        rad[0] = expf(-d0 * d0 * 18.0f);
        rad[1] = expf(-d1 * d1 * 18.0f);
        rad[2] = expf(-d2 * d2 * 18.0f);
        rad[3] = expf(-d3 * d3 * 18.0f);

        const int pm = p & 15;
#pragma unroll
        for (int r = 0; r < 4; ++r) {
            const float rr = rad[r];
#pragma unroll
            for (int k4 = 0; k4 < 4; ++k4) {
                const int col4 = (r * 4 + k4) ^ pm;     // swizzled physical col
                float4 v;
                v.x = Y[k4 * 4 + 0] * rr;
                v.y = Y[k4 * 4 + 1] * rr;
                v.z = Y[k4 * 4 + 2] * rr;
                v.w = Y[k4 * 4 + 3] * rr;
                *(float4*)&ck[p][col4 * 4] = v;
            }
        }

        float v = 0.28209479177387814f * rad[0];        // y_w contribution
#pragma unroll
        for (int off = 32; off > 0; off >>= 1) v += __shfl_down(v, off);
        if (p == 0) sh_yw = v;
    }
    __syncthreads();

    // ---- phase 2: gather signal, pre-scaled by 1/(y_w + 1e-6) ----
    const float inv_den = 1.0f / (sh_yw + 1e-6f);
#pragma unroll
    for (int pass = 0; pass < 4; ++pass) {
        const int row = (tid >> 4) + pass * 16;
        const int c4  = (tid & 15) * 4;
        float4 v = *(const float4*)&signal[(size_t)(b * NPTS + sIdx[row]) * CH + c4];
        v.x *= inv_den; v.y *= inv_den; v.z *= inv_den; v.w *= inv_den;
        *(float4*)&sigs[row][c4] = v;
    }
    __syncthreads();

    // ---- phase 3: thread owns (c, r); acc[16] over k ----
    const int c  = tid & 63;
    const int rq = tid >> 6;              // wave-uniform
    float acc[16];
#pragma unroll
    for (int i = 0; i < 16; ++i) acc[i] = 0.0f;

#pragma unroll 4
    for (int p = 0; p < PATCH; ++p) {
        const float s = sigs[p][c];
        const int pm = p & 15;
        const float4 k0 = *(const float4*)&ck[p][((rq * 4 + 0) ^ pm) * 4];
        const float4 k1 = *(const float4*)&ck[p][((rq * 4 + 1) ^ pm) * 4];
        const float4 k2 = *(const float4*)&ck[p][((rq * 4 + 2) ^ pm) * 4];
        const float4 k3 = *(const float4*)&ck[p][((rq * 4 + 3) ^ pm) * 4];
        acc[0]  = fmaf(s, k0.x, acc[0]);  acc[1]  = fmaf(s, k0.y, acc[1]);
        acc[2]  = fmaf(s, k0.z, acc[2]);  acc[3]  = fmaf(s, k0.w, acc[3]);
        acc[4]  = fmaf(s, k1.x, acc[4]);  acc[5]  = fmaf(s, k1.y, acc[5]);
        acc[6]  = fmaf(s, k1.z, acc[6]);  acc[7]  = fmaf(s, k1.w, acc[7]);
        acc[8]  = fmaf(s, k2.x, acc[8]);  acc[9]  = fmaf(s, k2.y, acc[9]);
        acc[10] = fmaf(s, k2.z, acc[10]); acc[11] = fmaf(s, k2.w, acc[11]);
        acc[12] = fmaf(s, k3.x, acc[12]); acc[13] = fmaf(s, k3.y, acc[13]);
        acc[14] = fmaf(s, k3.z, acc[14]); acc[15] = fmaf(s, k3.w, acc[15]);
    }

    // ---- phase 4: square + band-sum in registers ----
    const float l0 = acc[0] * acc[0];
    const float l1 = acc[1] * acc[1] + acc[2] * acc[2] + acc[3] * acc[3];
    const float l2 = acc[4] * acc[4] + acc[5] * acc[5] + acc[6] * acc[6]
                   + acc[7] * acc[7] + acc[8] * acc[8];
    const float l3 = acc[9] * acc[9] + acc[10] * acc[10] + acc[11] * acc[11]
                   + acc[12] * acc[12] + acc[13] * acc[13] + acc[14] * acc[14]
                   + acc[15] * acc[15];
    float4 zb;
    zb.x = sqrtf(fmaxf(l0, 1e-4f));
    zb.y = sqrtf(fmaxf(l1, 1e-4f));
    zb.z = sqrtf(fmaxf(l2, 1e-4f));
    zb.w = sqrtf(fmaxf(l3, 1e-4f));
    *(float4*)&z2[c * 16 + rq * 4] = zb;
    __syncthreads();

    // ---- phase 5: out[i] = sum_j WT[j*64+i] * z2[j] ----
    const int i_out = tid & 63;
    const int part  = tid >> 6;           // wave-uniform
    const float* wt = WT + (size_t)part * 256 * 64 + i_out;
    const float* zp = &z2[part * 256];
    float s = 0.0f;
#pragma unroll 8
    for (int j = 0; j < 256; ++j) s = fmaf(wt[(size_t)j * 64], zp[j], s);
    partial[part][i_out] = s;
    __syncthreads();
    if (tid < 64) {
        out[(size_t)pt * CH + tid] =
            partial[0][tid] + partial[1][tid] + partial[2][tid] + partial[3][tid] + biases[tid];
    }
}

extern "C" void kernel_launch(void* const* d_in, const int* in_sizes, int n_in,
                              void* d_out, int out_size, void* d_ws, size_t ws_size,
                              hipStream_t stream) {
    const float* xyz    = (const float*)d_in[0];
    const float* signal = (const float*)d_in[1];
    const float* weight = (const float*)d_in[2];
    const float* biases = (const float*)d_in[3];
    float* out = (float*)d_out;

    int*   knn_idx = (int*)d_ws;
    float* knn_sqd = (float*)((char*)d_ws + (size_t)NB * NPTS * PATCH * sizeof(int));
    float* WT      = (float*)((char*)d_ws + (size_t)2 * NB * NPTS * PATCH * sizeof(int));

    wtrans_kernel<<<256, 256, 0, stream>>>(weight, WT);
    knn_kernel<<<NB * NPTS, 256, 0, stream>>>(xyz, knn_idx, knn_sqd);
    conv_kernel<<<NB * NPTS, 256, 0, stream>>>(xyz, signal, WT, biases,
                                               knn_idx, knn_sqd, out);
}

// Round 3
// 141.158 us; speedup vs baseline: 15.8359x; 1.7714x over previous
//
#include <hip/hip_runtime.h>
#include <hip/hip_bf16.h>
#include <math.h>

#define NB 2
#define NPTS 4096
#define CH 64
#define PATCH 64

typedef __attribute__((ext_vector_type(8))) short s16x8;
typedef __attribute__((ext_vector_type(4))) short s16x4;
typedef __attribute__((ext_vector_type(4))) float f32x4;
typedef __attribute__((ext_vector_type(4))) unsigned u32x4;

static __device__ __forceinline__ short f2bf(float f) {
    union { __hip_bfloat16 h; short s; } u;
    u.h = __float2bfloat16(f);
    return u.s;
}

// ---------------------------------------------------------------------------
// Kernel 0: repack weight (64 x 1024 f32) into bf16 MFMA A-fragment order:
// Wfrag[(mt*32+st)*64 + lane][j] = bf16(W[mt*16+(lane&15)][st*32+(lane>>4)*8+j])
// ---------------------------------------------------------------------------
__global__ __launch_bounds__(256) void wprep_kernel(const float* __restrict__ W,
                                                    short* __restrict__ Wfrag) {
    const int gid = blockIdx.x * 256 + threadIdx.x;   // 8192 total
    const int mt = gid >> 11;
    const int st = (gid >> 6) & 31;
    const int l  = gid & 63;
    const int i  = mt * 16 + (l & 15);
    const int k0 = st * 32 + (l >> 4) * 8;
    const f32x4 a = *(const f32x4*)&W[i * 1024 + k0];
    const f32x4 c = *(const f32x4*)&W[i * 1024 + k0 + 4];
    s16x8 v;
    v[0] = f2bf(a[0]); v[1] = f2bf(a[1]); v[2] = f2bf(a[2]); v[3] = f2bf(a[3]);
    v[4] = f2bf(c[0]); v[5] = f2bf(c[1]); v[6] = f2bf(c[2]); v[7] = f2bf(c[3]);
    *(s16x8*)&Wfrag[gid * 8] = v;
}

// ---------------------------------------------------------------------------
// Kernel 1: exact 64-NN via 12/10/10-bit radix select with early exit.
// ---------------------------------------------------------------------------
__global__ __launch_bounds__(256, 4) void knn_kernel(const float* __restrict__ xyz,
                                                     int* __restrict__ knn_idx) {
    const int pt  = blockIdx.x;
    const int b   = pt >> 12;
    const int q   = pt & (NPTS - 1);
    const int tid = threadIdx.x;
    const int wv  = tid >> 6;
    const int lane = tid & 63;

    __shared__ __align__(16) float sd[NPTS];        // 16 KB
    __shared__ __align__(16) unsigned hist[4096];   // 16 KB
    __shared__ unsigned wsum[4];
    __shared__ unsigned sh_hi;
    __shared__ int sh_need, sh_shift, sh_done;
    __shared__ int cnt_less, cnt_tie;

    const float qx = xyz[(b * NPTS + q) * 3 + 0];
    const float qy = xyz[(b * NPTS + q) * 3 + 1];
    const float qz = xyz[(b * NPTS + q) * 3 + 2];

    for (int m = tid; m < NPTS; m += 256) {
        float dx = xyz[(b * NPTS + m) * 3 + 0] - qx;
        float dy = xyz[(b * NPTS + m) * 3 + 1] - qy;
        float dz = xyz[(b * NPTS + m) * 3 + 2] - qz;
        sd[m] = dx * dx + dy * dy + dz * dz;
    }
    if (tid == 0) {
        sh_hi = 0u; sh_need = PATCH; sh_shift = 20; sh_done = 0;
        cnt_less = 0; cnt_tie = 0;
    }
    __syncthreads();

    for (int pass = 0; pass < 3; ++pass) {
        if (sh_done) break;                    // uniform (read after barrier)
        const int shift = (pass == 0) ? 20 : (pass == 1) ? 10 : 0;
        const int nb    = (pass == 0) ? 4096 : 1024;
        for (int u = tid; u < (nb >> 2); u += 256)
            ((u32x4*)hist)[u] = (u32x4){0u, 0u, 0u, 0u};
        __syncthreads();
        const unsigned hi = sh_hi;
        for (int m = tid; m < NPTS; m += 256) {
            const unsigned key = __float_as_uint(sd[m]);
            const bool ok = (pass == 0) || ((key >> (shift + 10)) == hi);
            if (ok) atomicAdd(&hist[(key >> shift) & (nb - 1)], 1u);
        }
        __syncthreads();
        // --- select bin containing the need-th element ---
        const int g = nb >> 8;                 // bins per thread: 16 or 4
        unsigned tsum = 0;
#pragma unroll 4
        for (int u = 0; u < g; ++u) tsum += hist[tid * g + u];
        unsigned run = tsum;
#pragma unroll
        for (int off = 1; off < 64; off <<= 1) {
            unsigned v = __shfl_up(run, off);
            if (lane >= off) run += v;
        }
        if (lane == 63) wsum[wv] = run;
        __syncthreads();
        unsigned wbase = 0;
        for (int w2 = 0; w2 < wv; ++w2) wbase += wsum[w2];
        const unsigned incl = wbase + run;
        const unsigned excl = incl - tsum;
        const int need = sh_need;
        const unsigned hi_old = sh_hi;
        __syncthreads();                        // reads done before writes below
        if ((int)excl < need && need <= (int)incl) {
            int nrem = need - (int)excl;
            for (int u = 0; u < g; ++u) {
                const unsigned cb = hist[tid * g + u];
                if (nrem <= (int)cb) {
                    sh_hi = (pass == 0) ? (unsigned)(tid * g + u)
                                        : ((hi_old << 10) | (unsigned)(tid * g + u));
                    sh_need  = nrem;
                    sh_shift = shift;
                    if (nrem == (int)cb) sh_done = 1;
                    break;
                }
                nrem -= (int)cb;
            }
        }
        __syncthreads();
    }

    const unsigned H = sh_hi;
    const int S     = sh_shift;
    const int need  = sh_need;
    const int nless = PATCH - need;

    for (int m = tid; m < NPTS; m += 256) {
        const unsigned hk = __float_as_uint(sd[m]) >> S;
        if (hk < H) {
            int pos = atomicAdd(&cnt_less, 1);
            knn_idx[pt * PATCH + pos] = m;
        } else if (hk == H) {
            int pos = atomicAdd(&cnt_tie, 1);
            if (pos < need) knn_idx[pt * PATCH + nless + pos] = m;
        }
    }
}

// ---------------------------------------------------------------------------
// Kernel 2: conv. One block = 4 points processed sequentially (phases 1-4),
// then one shared MFMA epilogue so W is read once per 4 points.
//
// Main matmul per point: D[rk][c] = sum_p ck[p][rk] * sig[p][c]
//   via mfma_f32_16x16x32_bf16: A = ck (m=rk, k=p), B = sig (k=p, n=c).
//   Fragments are built K-contiguous in LDS, so the HW k-slot mapping cancels
//   between A and B; only m/n <-> lane&15 and the verified C/D layout matter.
// ---------------------------------------------------------------------------
__global__ __launch_bounds__(256, 4) void conv_kernel(const float* __restrict__ xyz,
                                                      const float* __restrict__ signal,
                                                      const short* __restrict__ Wfrag,
                                                      const float* __restrict__ biases,
                                                      const int* __restrict__ knn_idx,
                                                      float* __restrict__ out) {
    const int tid  = threadIdx.x;
    const int wv   = tid >> 6;
    const int lane = tid & 63;
    const int ln15 = lane & 15;
    const int kq   = lane >> 4;

    __shared__ __align__(16) short cks_bf[4096];  // 8 KB  [p][rk] swizzled, bf16
    __shared__ __align__(16) short ckF[4096];     // 8 KB  A-fragment order
    __shared__ __align__(16) short sigF[4096];    // 8 KB  B-fragment order
    __shared__ __align__(16) short zb[4 * 1032];  // 8.1 KB z rows (bf16), padded
    __shared__ int   sIdx[PATCH];
    __shared__ float sh_inv;

    for (int it = 0; it < 4; ++it) {
        const int pt = blockIdx.x * 4 + it;
        const int b  = pt >> 12;
        const int q  = pt & (NPTS - 1);

        if (tid < PATCH) sIdx[tid] = knn_idx[pt * PATCH + tid];
        __syncthreads();   // B1: sIdx ready; prev-iter LDS readers done

        if (wv == 0) {
            // ---- phase 1: SH + radial, ck products (bf16, swizzled) ----
            const int p   = lane;
            const int idx = sIdx[p];
            const float cx = xyz[(b * NPTS + q) * 3 + 0];
            const float cy = xyz[(b * NPTS + q) * 3 + 1];
            const float cz = xyz[(b * NPTS + q) * 3 + 2];
            const float dx = xyz[(b * NPTS + idx) * 3 + 0] - cx;
            const float dy = xyz[(b * NPTS + idx) * 3 + 1] - cy;
            const float dz = xyz[(b * NPTS + idx) * 3 + 2] - cz;
            const float nrm2 = dx * dx + dy * dy + dz * dz;
            const float inv_n = 1.0f / fmaxf(sqrtf(nrm2), 0.01f);
            const float x = dx * inv_n, y = dy * inv_n, z = dz * inv_n;
            const float x2 = x * x, y2 = y * y, zz = z * z;

            float Y[16];
            Y[0] = 0.28209479177387814f;
            const float s3 = 0.4886025119029199f;
            Y[1] = s3 * y;  Y[2] = s3 * z;  Y[3] = -s3 * x;
            const float s15h = 1.0925484305920792f;
            const float s15q = 0.5462742152960396f;
            const float s5q  = 0.31539156525252005f;
            Y[4] = s15h * x * y;
            Y[5] = s15h * y * z;
            Y[6] = s5q * (2.0f * zz - x2 - y2);
            Y[7] = -s15h * z * x;
            Y[8] = s15q * (x2 - y2);
            const float c33  = 0.5900435899266435f;
            const float c32  = 2.8906114426405543f;
            const float c31  = 0.4570457994644658f;
            const float c30  = 0.3731763325901154f;
            const float c32b = 1.4453057213202771f;
            Y[9]  = c33 * (3.0f * x2 * y - y * y2);
            Y[10] = c32 * x * y * z;
            Y[11] = c31 * (4.0f * y * zz - x2 * y - y * y2);
            Y[12] = c30 * (2.0f * z * zz - 3.0f * x2 * z - 3.0f * y2 * z);
            Y[13] = -c31 * (4.0f * zz * x - x * x2 - x * y2);
            Y[14] = c32b * (x2 * z - y2 * z);
            Y[15] = -c33 * (x * x2 - 3.0f * x * y2);

            const float dist = sqrtf(fmaxf(nrm2, 1e-4f));
            const float d1 = dist - 0.16666667f;
            const float d2 = dist - 0.33333334f;
            const float d3 = dist - 0.5f;
            float rad[4];
            rad[0] = expf(-dist * dist * 18.0f);
            rad[1] = expf(-d1 * d1 * 18.0f);
            rad[2] = expf(-d2 * d2 * 18.0f);
            rad[3] = expf(-d3 * d3 * 18.0f);

            const int pm = p & 15;
#pragma unroll
            for (int chunk = 0; chunk < 16; ++chunk) {
                const int r  = chunk >> 2;
                const int kb = (chunk & 3) * 4;
                s16x4 v;
                v[0] = f2bf(Y[kb + 0] * rad[r]);
                v[1] = f2bf(Y[kb + 1] * rad[r]);
                v[2] = f2bf(Y[kb + 2] * rad[r]);
                v[3] = f2bf(Y[kb + 3] * rad[r]);
                *(s16x4*)&cks_bf[p * 64 + ((chunk ^ pm) << 2)] = v;
            }
            float v = 0.28209479177387814f * rad[0];
#pragma unroll
            for (int off = 32; off > 0; off >>= 1) v += __shfl_down(v, off);
            if (p == 0) sh_inv = 1.0f / (v + 1e-6f);
        } else {
            // ---- phase 2: gather signal into B-fragment order (bf16) ----
            const int r0 = (wv - 1) * 3;
            const int rn = (wv == 3) ? 2 : 3;
            for (int rr = 0; rr < rn; ++rr) {
                const int rd = r0 + rr;
                const int ct = rd >> 1, s = rd & 1;
                const int c  = ct * 16 + ln15;
                const int pb = s * 32 + kq * 8;
                s16x8 sv;
#pragma unroll
                for (int j = 0; j < 8; ++j) {
                    const float f = signal[(size_t)(b * NPTS + sIdx[pb + j]) * CH + c];
                    sv[j] = f2bf(f);
                }
                *(s16x8*)&sigF[(ct * 2 + s) * 512 + lane * 8] = sv;
            }
        }
        __syncthreads();   // B2

        // ---- phase 2b: repack ck into A-fragment order ----
#pragma unroll
        for (int ff = 0; ff < 2; ++ff) {
            const int f  = wv + ff * 4;
            const int mt = f >> 1, s = f & 1;
            const int rk = mt * 16 + ln15;
            const int rsw = rk >> 2, rlo = rk & 3;
            const int pb = s * 32 + kq * 8;
            s16x8 av;
#pragma unroll
            for (int j = 0; j < 8; ++j) {
                const int p = pb + j;
                av[j] = cks_bf[p * 64 + ((rsw ^ (p & 15)) << 2) + rlo];
            }
            *(s16x8*)&ckF[f * 512 + lane * 8] = av;
        }
        __syncthreads();   // B3

        // ---- phase 3: MFMA main matmul; wave wv owns c-tile ct=wv ----
        const s16x8 bf0 = *(const s16x8*)&sigF[(wv * 2 + 0) * 512 + lane * 8];
        const s16x8 bf1 = *(const s16x8*)&sigF[(wv * 2 + 1) * 512 + lane * 8];
        f32x4 acc0 = {0.f, 0.f, 0.f, 0.f}, acc1 = acc0, acc2 = acc0, acc3 = acc0;
        {
            s16x8 a;
            a = *(const s16x8*)&ckF[0 * 512 + lane * 8];
            acc0 = __builtin_amdgcn_mfma_f32_16x16x32_bf16(a, bf0, acc0, 0, 0, 0);
            a = *(const s16x8*)&ckF[1 * 512 + lane * 8];
            acc0 = __builtin_amdgcn_mfma_f32_16x16x32_bf16(a, bf1, acc0, 0, 0, 0);
            a = *(const s16x8*)&ckF[2 * 512 + lane * 8];
            acc1 = __builtin_amdgcn_mfma_f32_16x16x32_bf16(a, bf0, acc1, 0, 0, 0);
            a = *(const s16x8*)&ckF[3 * 512 + lane * 8];
            acc1 = __builtin_amdgcn_mfma_f32_16x16x32_bf16(a, bf1, acc1, 0, 0, 0);
            a = *(const s16x8*)&ckF[4 * 512 + lane * 8];
            acc2 = __builtin_amdgcn_mfma_f32_16x16x32_bf16(a, bf0, acc2, 0, 0, 0);
            a = *(const s16x8*)&ckF[5 * 512 + lane * 8];
            acc2 = __builtin_amdgcn_mfma_f32_16x16x32_bf16(a, bf1, acc2, 0, 0, 0);
            a = *(const s16x8*)&ckF[6 * 512 + lane * 8];
            acc3 = __builtin_amdgcn_mfma_f32_16x16x32_bf16(a, bf0, acc3, 0, 0, 0);
            a = *(const s16x8*)&ckF[7 * 512 + lane * 8];
            acc3 = __builtin_amdgcn_mfma_f32_16x16x32_bf16(a, bf1, acc3, 0, 0, 0);
        }

        // ---- phase 4: scale, square, band-sum (xor-reduce over k-quads) ----
        const float inv = sh_inv;
        const int qq = kq;
        float rb[4][4];
#pragma unroll
        for (int mt = 0; mt < 4; ++mt) {
            f32x4 av = (mt == 0) ? acc0 : (mt == 1) ? acc1 : (mt == 2) ? acc2 : acc3;
            const float y0 = av[0] * inv, y1 = av[1] * inv;
            const float y2 = av[2] * inv, y3 = av[3] * inv;
            const float sA = y0 * y0;
            const float sB = y1 * y1 + y2 * y2 + y3 * y3;
            const float sAll = sA + sB;
            float b0 = (qq == 0) ? sA : 0.0f;
            float b1 = (qq == 0) ? sB : 0.0f;
            float b2 = (qq == 1) ? sAll : ((qq == 2) ? sA : 0.0f);
            float b3 = (qq == 3) ? sAll : ((qq == 2) ? sB : 0.0f);
            b0 += __shfl_xor(b0, 16); b0 += __shfl_xor(b0, 32);
            b1 += __shfl_xor(b1, 16); b1 += __shfl_xor(b1, 32);
            b2 += __shfl_xor(b2, 16); b2 += __shfl_xor(b2, 32);
            b3 += __shfl_xor(b3, 16); b3 += __shfl_xor(b3, 32);
            rb[mt][0] = b0; rb[mt][1] = b1; rb[mt][2] = b2; rb[mt][3] = b3;
        }
        // lane handles r = qq: select bands of mt == qq (static unroll -> cndmask)
        float s0 = rb[0][0], s1 = rb[0][1], s2 = rb[0][2], s3 = rb[0][3];
#pragma unroll
        for (int mt = 1; mt < 4; ++mt) {
            s0 = (qq == mt) ? rb[mt][0] : s0;
            s1 = (qq == mt) ? rb[mt][1] : s1;
            s2 = (qq == mt) ? rb[mt][2] : s2;
            s3 = (qq == mt) ? rb[mt][3] : s3;
        }
        s16x4 zv;
        zv[0] = f2bf(sqrtf(fmaxf(s0, 1e-4f)));
        zv[1] = f2bf(sqrtf(fmaxf(s1, 1e-4f)));
        zv[2] = f2bf(sqrtf(fmaxf(s2, 1e-4f)));
        zv[3] = f2bf(sqrtf(fmaxf(s3, 1e-4f)));
        const int c = wv * 16 + ln15;
        *(s16x4*)&zb[it * 1032 + c * 16 + qq * 4] = zv;
    }
    __syncthreads();   // B4: all z rows ready

    // ---- phase 5: out[i] = sum_j W[i][j] z[j] via MFMA, 4 points batched ----
    const int mt5 = wv;
    const int g   = ln15 & 3;
    f32x4 acc5 = {0.f, 0.f, 0.f, 0.f};
#pragma unroll 4
    for (int st = 0; st < 32; ++st) {
        const s16x8 a  = *(const s16x8*)&Wfrag[((mt5 * 32 + st) * 64 + lane) * 8];
        const s16x8 zf = *(const s16x8*)&zb[g * 1032 + st * 32 + kq * 8];
        acc5 = __builtin_amdgcn_mfma_f32_16x16x32_bf16(a, zf, acc5, 0, 0, 0);
    }
    if (ln15 < 4) {
        const int i0 = mt5 * 16 + kq * 4;
        const int orow = (blockIdx.x * 4 + g) * CH;
#pragma unroll
        for (int rg = 0; rg < 4; ++rg)
            out[orow + i0 + rg] = acc5[rg] + biases[i0 + rg];
    }
}

extern "C" void kernel_launch(void* const* d_in, const int* in_sizes, int n_in,
                              void* d_out, int out_size, void* d_ws, size_t ws_size,
                              hipStream_t stream) {
    const float* xyz    = (const float*)d_in[0];
    const float* signal = (const float*)d_in[1];
    const float* weight = (const float*)d_in[2];
    const float* biases = (const float*)d_in[3];
    float* out = (float*)d_out;

    int*   knn_idx = (int*)d_ws;                                      // 2 MB
    short* Wfrag   = (short*)((char*)d_ws + (size_t)NB * NPTS * PATCH * sizeof(int));

    wprep_kernel<<<32, 256, 0, stream>>>(weight, Wfrag);
    knn_kernel<<<NB * NPTS, 256, 0, stream>>>(xyz, knn_idx);
    conv_kernel<<<(NB * NPTS) / 4, 256, 0, stream>>>(xyz, signal, Wfrag, biases,
                                                     knn_idx, out);
}

// Round 4
// 92.330 us; speedup vs baseline: 24.2106x; 1.5288x over previous
//
#include <hip/hip_runtime.h>
#include <hip/hip_bf16.h>
#include <math.h>

#define NB 2
#define NPTS 4096
#define CH 64
#define PATCH 64

typedef __attribute__((ext_vector_type(8))) short s16x8;
typedef __attribute__((ext_vector_type(4))) short s16x4;
typedef __attribute__((ext_vector_type(4))) float f32x4;
typedef __attribute__((ext_vector_type(4))) unsigned u32x4;

static __device__ __forceinline__ short f2bf(float f) {
    union { __hip_bfloat16 h; short s; } u;
    u.h = __float2bfloat16(f);
    return u.s;
}

// ---------------------------------------------------------------------------
// Kernel 0: repack weight (64 x 1024 f32) into bf16 MFMA A-fragment order:
// Wfrag[(mt*32+st)*64 + lane][j] = bf16(W[mt*16+(lane&15)][st*32+(lane>>4)*8+j])
// ---------------------------------------------------------------------------
__global__ __launch_bounds__(256) void wprep_kernel(const float* __restrict__ W,
                                                    short* __restrict__ Wfrag) {
    const int gid = blockIdx.x * 256 + threadIdx.x;   // 8192 total
    const int mt = gid >> 11;
    const int st = (gid >> 6) & 31;
    const int l  = gid & 63;
    const int i  = mt * 16 + (l & 15);
    const int k0 = st * 32 + (l >> 4) * 8;
    const f32x4 a = *(const f32x4*)&W[i * 1024 + k0];
    const f32x4 c = *(const f32x4*)&W[i * 1024 + k0 + 4];
    s16x8 v;
    v[0] = f2bf(a[0]); v[1] = f2bf(a[1]); v[2] = f2bf(a[2]); v[3] = f2bf(a[3]);
    v[4] = f2bf(c[0]); v[5] = f2bf(c[1]); v[6] = f2bf(c[2]); v[7] = f2bf(c[3]);
    *(s16x8*)&Wfrag[gid * 8] = v;
}

// ---------------------------------------------------------------------------
// Kernel 1: exact 64-NN, single-pass 12-bit histogram select.
//   - distances recomputed (not staged) -> LDS = 16.5 KB -> 8 blocks/CU
//   - one histogram on float-key bits [30:19] (monotone for positive floats)
//   - boundary bin resolved exactly via tiny rank-select on full 32-bit keys
// ---------------------------------------------------------------------------
__global__ __launch_bounds__(256, 8) void knn_kernel(const float* __restrict__ xyz,
                                                     int* __restrict__ knn_idx) {
    const int pt   = blockIdx.x;
    const int b    = pt >> 12;
    const int q    = pt & (NPTS - 1);
    const int tid  = threadIdx.x;
    const int wv   = tid >> 6;
    const int lane = tid & 63;

    __shared__ __align__(16) unsigned hist[4096];   // 16 KB; reused for candidates
    __shared__ unsigned wsum[4];
    __shared__ unsigned sh_H;
    __shared__ int sh_need;
    __shared__ int cnt_less, cnt_tie;

    const float* xb = xyz + (size_t)b * NPTS * 3;
    const float qx = xb[q * 3 + 0];
    const float qy = xb[q * 3 + 1];
    const float qz = xb[q * 3 + 2];

#pragma unroll
    for (int u = 0; u < 4; ++u)
        ((u32x4*)hist)[u * 256 + tid] = (u32x4){0u, 0u, 0u, 0u};
    if (tid == 0) { cnt_less = 0; cnt_tie = 0; }
    __syncthreads();

    // ---- histogram fill ----
    for (int m = tid; m < NPTS; m += 256) {
        const float dx = xb[m * 3 + 0] - qx;
        const float dy = xb[m * 3 + 1] - qy;
        const float dz = xb[m * 3 + 2] - qz;
        const float sq = fmaf(dx, dx, fmaf(dy, dy, dz * dz));
        atomicAdd(&hist[__float_as_uint(sq) >> 19], 1u);
    }
    __syncthreads();

    // ---- scan: thread t owns bins [16t, 16t+16) ----
    unsigned tsum = 0;
#pragma unroll
    for (int u = 0; u < 4; ++u) {
        const u32x4 h4 = ((const u32x4*)hist)[tid * 4 + u];
        tsum += h4[0] + h4[1] + h4[2] + h4[3];
    }
    unsigned run = tsum;
#pragma unroll
    for (int off = 1; off < 64; off <<= 1) {
        const unsigned v = __shfl_up(run, off);
        if (lane >= off) run += v;
    }
    if (lane == 63) wsum[wv] = run;
    __syncthreads();
    unsigned wbase = 0;
    for (int w2 = 0; w2 < wv; ++w2) wbase += wsum[w2];
    const unsigned incl = wbase + run;
    const unsigned excl = incl - tsum;
    if ((int)excl < PATCH && PATCH <= (int)incl) {   // unique crossing thread
        int nrem = PATCH - (int)excl;
        for (int u = 0; u < 16; ++u) {
            const unsigned cb = hist[tid * 16 + u];
            if (nrem <= (int)cb) { sh_H = (unsigned)(tid * 16 + u); sh_need = nrem; break; }
            nrem -= (int)cb;
        }
    }
    __syncthreads();

    const unsigned H = sh_H;
    const int need  = sh_need;
    const int nless = PATCH - need;
    unsigned* ckey = hist;            // reuse histogram LDS for candidates
    unsigned* cidx = hist + 2048;

    // ---- extraction ----
    for (int m = tid; m < NPTS; m += 256) {
        const float dx = xb[m * 3 + 0] - qx;
        const float dy = xb[m * 3 + 1] - qy;
        const float dz = xb[m * 3 + 2] - qz;
        const float sq = fmaf(dx, dx, fmaf(dy, dy, dz * dz));
        const unsigned key = __float_as_uint(sq);
        const unsigned hk = key >> 19;
        if (hk < H) {
            const int pos = atomicAdd(&cnt_less, 1);
            knn_idx[pt * PATCH + pos] = m;
        } else if (hk == H) {
            const int pos = atomicAdd(&cnt_tie, 1);
            if (pos < 2048) { ckey[pos] = key; cidx[pos] = m; }
        }
    }
    __syncthreads();

    // ---- exact rank-select within boundary bin (nc typically ~6) ----
    const int nc = min(cnt_tie, 2048);
    for (int i = tid; i < nc; i += 256) {
        const unsigned ki = ckey[i];
        int rank = 0;
        for (int j = 0; j < nc; ++j) {          // uniform j -> LDS broadcast
            const unsigned kj = ckey[j];
            rank += (kj < ki || (kj == ki && j < i)) ? 1 : 0;
        }
        if (rank < need) knn_idx[pt * PATCH + nless + rank] = cidx[i];
    }
}

// ---------------------------------------------------------------------------
// Kernel 2: conv. One block = 4 points processed sequentially (phases 1-4),
// then one shared MFMA epilogue so W is read once per 4 points.
// ---------------------------------------------------------------------------
__global__ __launch_bounds__(256, 4) void conv_kernel(const float* __restrict__ xyz,
                                                      const float* __restrict__ signal,
                                                      const short* __restrict__ Wfrag,
                                                      const float* __restrict__ biases,
                                                      const int* __restrict__ knn_idx,
                                                      float* __restrict__ out) {
    const int tid  = threadIdx.x;
    const int wv   = tid >> 6;
    const int lane = tid & 63;
    const int ln15 = lane & 15;
    const int kq   = lane >> 4;

    __shared__ __align__(16) short cks_bf[4096];  // 8 KB  [p][rk] swizzled, bf16
    __shared__ __align__(16) short ckF[4096];     // 8 KB  A-fragment order
    __shared__ __align__(16) short sigF[4096];    // 8 KB  B-fragment order
    __shared__ __align__(16) short zb[4 * 1032];  // 8.1 KB z rows (bf16), padded
    __shared__ int   sIdx[PATCH];
    __shared__ float sh_inv;

    for (int it = 0; it < 4; ++it) {
        const int pt = blockIdx.x * 4 + it;
        const int b  = pt >> 12;
        const int q  = pt & (NPTS - 1);

        if (tid < PATCH) sIdx[tid] = knn_idx[pt * PATCH + tid];
        __syncthreads();   // B1: sIdx ready; prev-iter LDS readers done

        if (wv == 0) {
            // ---- phase 1: SH + radial, ck products (bf16, swizzled) ----
            const int p   = lane;
            const int idx = sIdx[p];
            const float cx = xyz[(b * NPTS + q) * 3 + 0];
            const float cy = xyz[(b * NPTS + q) * 3 + 1];
            const float cz = xyz[(b * NPTS + q) * 3 + 2];
            const float dx = xyz[(b * NPTS + idx) * 3 + 0] - cx;
            const float dy = xyz[(b * NPTS + idx) * 3 + 1] - cy;
            const float dz = xyz[(b * NPTS + idx) * 3 + 2] - cz;
            const float nrm2 = dx * dx + dy * dy + dz * dz;
            const float inv_n = 1.0f / fmaxf(sqrtf(nrm2), 0.01f);
            const float x = dx * inv_n, y = dy * inv_n, z = dz * inv_n;
            const float x2 = x * x, y2 = y * y, zz = z * z;

            float Y[16];
            Y[0] = 0.28209479177387814f;
            const float s3 = 0.4886025119029199f;
            Y[1] = s3 * y;  Y[2] = s3 * z;  Y[3] = -s3 * x;
            const float s15h = 1.0925484305920792f;
            const float s15q = 0.5462742152960396f;
            const float s5q  = 0.31539156525252005f;
            Y[4] = s15h * x * y;
            Y[5] = s15h * y * z;
            Y[6] = s5q * (2.0f * zz - x2 - y2);
            Y[7] = -s15h * z * x;
            Y[8] = s15q * (x2 - y2);
            const float c33  = 0.5900435899266435f;
            const float c32  = 2.8906114426405543f;
            const float c31  = 0.4570457994644658f;
            const float c30  = 0.3731763325901154f;
            const float c32b = 1.4453057213202771f;
            Y[9]  = c33 * (3.0f * x2 * y - y * y2);
            Y[10] = c32 * x * y * z;
            Y[11] = c31 * (4.0f * y * zz - x2 * y - y * y2);
            Y[12] = c30 * (2.0f * z * zz - 3.0f * x2 * z - 3.0f * y2 * z);
            Y[13] = -c31 * (4.0f * zz * x - x * x2 - x * y2);
            Y[14] = c32b * (x2 * z - y2 * z);
            Y[15] = -c33 * (x * x2 - 3.0f * x * y2);

            const float dist = sqrtf(fmaxf(nrm2, 1e-4f));
            const float d1 = dist - 0.16666667f;
            const float d2 = dist - 0.33333334f;
            const float d3 = dist - 0.5f;
            float rad[4];
            rad[0] = expf(-dist * dist * 18.0f);
            rad[1] = expf(-d1 * d1 * 18.0f);
            rad[2] = expf(-d2 * d2 * 18.0f);
            rad[3] = expf(-d3 * d3 * 18.0f);

            const int pm = p & 15;
#pragma unroll
            for (int chunk = 0; chunk < 16; ++chunk) {
                const int r  = chunk >> 2;
                const int kb = (chunk & 3) * 4;
                s16x4 v;
                v[0] = f2bf(Y[kb + 0] * rad[r]);
                v[1] = f2bf(Y[kb + 1] * rad[r]);
                v[2] = f2bf(Y[kb + 2] * rad[r]);
                v[3] = f2bf(Y[kb + 3] * rad[r]);
                *(s16x4*)&cks_bf[p * 64 + ((chunk ^ pm) << 2)] = v;
            }
            float v = 0.28209479177387814f * rad[0];
#pragma unroll
            for (int off = 32; off > 0; off >>= 1) v += __shfl_down(v, off);
            if (p == 0) sh_inv = 1.0f / (v + 1e-6f);
        } else {
            // ---- phase 2: gather signal into B-fragment order (bf16) ----
            const int r0 = (wv - 1) * 3;
            const int rn = (wv == 3) ? 2 : 3;
            for (int rr = 0; rr < rn; ++rr) {
                const int rd = r0 + rr;
                const int ct = rd >> 1, s = rd & 1;
                const int c  = ct * 16 + ln15;
                const int pb = s * 32 + kq * 8;
                s16x8 sv;
#pragma unroll
                for (int j = 0; j < 8; ++j) {
                    const float f = signal[(size_t)(b * NPTS + sIdx[pb + j]) * CH + c];
                    sv[j] = f2bf(f);
                }
                *(s16x8*)&sigF[(ct * 2 + s) * 512 + lane * 8] = sv;
            }
        }
        __syncthreads();   // B2

        // ---- phase 2b: repack ck into A-fragment order ----
#pragma unroll
        for (int ff = 0; ff < 2; ++ff) {
            const int f  = wv + ff * 4;
            const int mt = f >> 1, s = f & 1;
            const int rk = mt * 16 + ln15;
            const int rsw = rk >> 2, rlo = rk & 3;
            const int pb = s * 32 + kq * 8;
            s16x8 av;
#pragma unroll
            for (int j = 0; j < 8; ++j) {
                const int p = pb + j;
                av[j] = cks_bf[p * 64 + ((rsw ^ (p & 15)) << 2) + rlo];
            }
            *(s16x8*)&ckF[f * 512 + lane * 8] = av;
        }
        __syncthreads();   // B3

        // ---- phase 3: MFMA main matmul; wave wv owns c-tile ct=wv ----
        const s16x8 bf0 = *(const s16x8*)&sigF[(wv * 2 + 0) * 512 + lane * 8];
        const s16x8 bf1 = *(const s16x8*)&sigF[(wv * 2 + 1) * 512 + lane * 8];
        f32x4 acc0 = {0.f, 0.f, 0.f, 0.f}, acc1 = acc0, acc2 = acc0, acc3 = acc0;
        {
            s16x8 a;
            a = *(const s16x8*)&ckF[0 * 512 + lane * 8];
            acc0 = __builtin_amdgcn_mfma_f32_16x16x32_bf16(a, bf0, acc0, 0, 0, 0);
            a = *(const s16x8*)&ckF[1 * 512 + lane * 8];
            acc0 = __builtin_amdgcn_mfma_f32_16x16x32_bf16(a, bf1, acc0, 0, 0, 0);
            a = *(const s16x8*)&ckF[2 * 512 + lane * 8];
            acc1 = __builtin_amdgcn_mfma_f32_16x16x32_bf16(a, bf0, acc1, 0, 0, 0);
            a = *(const s16x8*)&ckF[3 * 512 + lane * 8];
            acc1 = __builtin_amdgcn_mfma_f32_16x16x32_bf16(a, bf1, acc1, 0, 0, 0);
            a = *(const s16x8*)&ckF[4 * 512 + lane * 8];
            acc2 = __builtin_amdgcn_mfma_f32_16x16x32_bf16(a, bf0, acc2, 0, 0, 0);
            a = *(const s16x8*)&ckF[5 * 512 + lane * 8];
            acc2 = __builtin_amdgcn_mfma_f32_16x16x32_bf16(a, bf1, acc2, 0, 0, 0);
            a = *(const s16x8*)&ckF[6 * 512 + lane * 8];
            acc3 = __builtin_amdgcn_mfma_f32_16x16x32_bf16(a, bf0, acc3, 0, 0, 0);
            a = *(const s16x8*)&ckF[7 * 512 + lane * 8];
            acc3 = __builtin_amdgcn_mfma_f32_16x16x32_bf16(a, bf1, acc3, 0, 0, 0);
        }

        // ---- phase 4: scale, square, band-sum (xor-reduce over k-quads) ----
        const float inv = sh_inv;
        const int qq = kq;
        float rb[4][4];
#pragma unroll
        for (int mt = 0; mt < 4; ++mt) {
            f32x4 av = (mt == 0) ? acc0 : (mt == 1) ? acc1 : (mt == 2) ? acc2 : acc3;
            const float y0 = av[0] * inv, y1 = av[1] * inv;
            const float y2 = av[2] * inv, y3 = av[3] * inv;
            const float sA = y0 * y0;
            const float sB = y1 * y1 + y2 * y2 + y3 * y3;
            const float sAll = sA + sB;
            float b0 = (qq == 0) ? sA : 0.0f;
            float b1 = (qq == 0) ? sB : 0.0f;
            float b2 = (qq == 1) ? sAll : ((qq == 2) ? sA : 0.0f);
            float b3 = (qq == 3) ? sAll : ((qq == 2) ? sB : 0.0f);
            b0 += __shfl_xor(b0, 16); b0 += __shfl_xor(b0, 32);
            b1 += __shfl_xor(b1, 16); b1 += __shfl_xor(b1, 32);
            b2 += __shfl_xor(b2, 16); b2 += __shfl_xor(b2, 32);
            b3 += __shfl_xor(b3, 16); b3 += __shfl_xor(b3, 32);
            rb[mt][0] = b0; rb[mt][1] = b1; rb[mt][2] = b2; rb[mt][3] = b3;
        }
        float s0 = rb[0][0], s1 = rb[0][1], s2 = rb[0][2], s3 = rb[0][3];
#pragma unroll
        for (int mt = 1; mt < 4; ++mt) {
            s0 = (qq == mt) ? rb[mt][0] : s0;
            s1 = (qq == mt) ? rb[mt][1] : s1;
            s2 = (qq == mt) ? rb[mt][2] : s2;
            s3 = (qq == mt) ? rb[mt][3] : s3;
        }
        s16x4 zv;
        zv[0] = f2bf(sqrtf(fmaxf(s0, 1e-4f)));
        zv[1] = f2bf(sqrtf(fmaxf(s1, 1e-4f)));
        zv[2] = f2bf(sqrtf(fmaxf(s2, 1e-4f)));
        zv[3] = f2bf(sqrtf(fmaxf(s3, 1e-4f)));
        const int c = wv * 16 + ln15;
        *(s16x4*)&zb[it * 1032 + c * 16 + qq * 4] = zv;
    }
    __syncthreads();   // B4: all z rows ready

    // ---- phase 5: out[i] = sum_j W[i][j] z[j] via MFMA, 4 points batched ----
    const int mt5 = wv;
    const int g   = ln15 & 3;
    f32x4 acc5 = {0.f, 0.f, 0.f, 0.f};
#pragma unroll 4
    for (int st = 0; st < 32; ++st) {
        const s16x8 a  = *(const s16x8*)&Wfrag[((mt5 * 32 + st) * 64 + lane) * 8];
        const s16x8 zf = *(const s16x8*)&zb[g * 1032 + st * 32 + kq * 8];
        acc5 = __builtin_amdgcn_mfma_f32_16x16x32_bf16(a, zf, acc5, 0, 0, 0);
    }
    if (ln15 < 4) {
        const int i0 = mt5 * 16 + kq * 4;
        const int orow = (blockIdx.x * 4 + g) * CH;
#pragma unroll
        for (int rg = 0; rg < 4; ++rg)
            out[orow + i0 + rg] = acc5[rg] + biases[i0 + rg];
    }
}

extern "C" void kernel_launch(void* const* d_in, const int* in_sizes, int n_in,
                              void* d_out, int out_size, void* d_ws, size_t ws_size,
                              hipStream_t stream) {
    const float* xyz    = (const float*)d_in[0];
    const float* signal = (const float*)d_in[1];
    const float* weight = (const float*)d_in[2];
    const float* biases = (const float*)d_in[3];
    float* out = (float*)d_out;

    int*   knn_idx = (int*)d_ws;                                      // 2 MB
    short* Wfrag   = (short*)((char*)d_ws + (size_t)NB * NPTS * PATCH * sizeof(int));

    wprep_kernel<<<32, 256, 0, stream>>>(weight, Wfrag);
    knn_kernel<<<NB * NPTS, 256, 0, stream>>>(xyz, knn_idx);
    conv_kernel<<<(NB * NPTS) / 4, 256, 0, stream>>>(xyz, signal, Wfrag, biases,
                                                     knn_idx, out);
}